// Round 5
// baseline (863.612 us; speedup 1.0000x reference)
//
#include <hip/hip_runtime.h>

#define SHIFT 4

typedef short bf16x8 __attribute__((ext_vector_type(8)));
typedef float f32x4  __attribute__((ext_vector_type(4)));

#define MFMA(a, b, c) __builtin_amdgcn_mfma_f32_16x16x32_bf16((a), (b), (c), 0, 0, 0)

__device__ __forceinline__ unsigned short f2bf(float f) {
  unsigned int u = __float_as_uint(f);
  u += 0x7fffu + ((u >> 16) & 1u);   // round-to-nearest-even; inputs finite
  return (unsigned short)(u >> 16);
}
__device__ __forceinline__ float bf2f(unsigned short u) {
  return __uint_as_float(((unsigned int)u) << 16);
}

// ---------------------------------------------------------------------------
// Kernel 0: fp32 -> bf16 weight conversion
// ---------------------------------------------------------------------------
__global__ void k_cvt(const float* __restrict__ s, unsigned short* __restrict__ d, int n) {
  int i = blockIdx.x * blockDim.x + threadIdx.x;
  int st = gridDim.x * blockDim.x;
  for (; i < n; i += st) d[i] = f2bf(s[i]);
}

// ---------------------------------------------------------------------------
// Kernel 1: per-window  LN1 + shift-gather + QKV + attention + proj + shortcut
// Emits xt = x + attn (bf16, TOKEN-MAJOR [B*HW][96], original coordinates).
// grid = 8192, block = 256 (4 waves; wave = 16-row M-tile). 1 barrier.
// LDS = R1(13312)+Ks(13312)+Vt(13824) = 40448 B -> 4 blocks/CU
// ---------------------------------------------------------------------------
__global__ __launch_bounds__(256, 4) void k_attn(
    const float* __restrict__ x,
    const float* __restrict__ ln1g, const float* __restrict__ ln1b,
    const unsigned short* __restrict__ qkvw,   // bf16 [288][96]
    const float* __restrict__ qkvb,
    const float* __restrict__ lapA, const float* __restrict__ lapB,
    const unsigned short* __restrict__ projw,  // bf16 [96][96]
    const float* __restrict__ projb,
    unsigned short* __restrict__ xt)           // bf16 [2*512*512][96]
{
  // R1 multiplexes (stride 104, rows wave-band-private): Xb -> Q -> P -> O -> proj
  __shared__ __align__(16) unsigned short R1[64 * 104];
  __shared__ __align__(16) unsigned short Ks[64 * 104];
  __shared__ __align__(16) unsigned short Vt[96 * 72];   // V^T [d][key(+pad)]

  const int tid = threadIdx.x;
  const int wid = blockIdx.x;
  const int b   = wid >> 12;
  const int hi  = (wid >> 6) & 63;
  const int wi  = wid & 63;
  const int q   = tid & 3;        // channel quarter (24 channels)
  const int t   = tid >> 2;       // owned token 0..63 (inside own wave's band)
  const int lane = tid & 63;
  const int wv   = tid >> 6;
  const int l16  = lane & 15;
  const int lg   = lane >> 4;
  const int arow = wv * 16 + l16;
  const f32x4 zz = {0.f, 0.f, 0.f, 0.f};

  const int sh = ((hi & 1) == 0) ? -SHIFT : SHIFT;   // gather source offset

  // ---- shifted gather into registers: thread owns (t, c = q*24 + k) ----
  // xreg stays live to the end (it IS the shortcut at this token's position).
  float xreg[24];
  {
    const int hh = hi * 8 + (t >> 3);
    const int ww = ((wi * 8 + (t & 7)) + sh) & 511;
    const float* xp = x + (hh << 9) + ww;
#pragma unroll
    for (int k = 0; k < 24; ++k)
      xreg[k] = xp[(b * 96 + q * 24 + k) << 18];
  }
  // ---- LN1 stats via quad shuffles ----
  float mu, rs;
  {
    float s1 = 0.f, s2 = 0.f;
#pragma unroll
    for (int k = 0; k < 24; ++k) { float v = xreg[k]; s1 += v; s2 += v * v; }
    s1 += __shfl_xor(s1, 1); s2 += __shfl_xor(s2, 1);
    s1 += __shfl_xor(s1, 2); s2 += __shfl_xor(s2, 2);
    mu = s1 * (1.f / 96.f);
    rs = rsqrtf(s2 * (1.f / 96.f) - mu * mu + 1e-5f);
  }
  // ---- Xb into R1 (vectorized, band-private) ----
#pragma unroll
  for (int v = 0; v < 3; ++v) {
    bf16x8 pk;
#pragma unroll
    for (int e = 0; e < 8; ++e) {
      int c = q * 24 + v * 8 + e;
      pk[e] = (short)f2bf((xreg[v * 8 + e] - mu) * rs * ln1g[c] + ln1b[c]);
    }
    *reinterpret_cast<bf16x8*>(&R1[t * 104 + q * 24 + v * 8]) = pk;
  }

  // ---- QKV GEMM: [64,96] @ [96,288]^T  (A-frags from own band; no barrier) ----
  bf16x8 afr[3];
#pragma unroll
  for (int ks = 0; ks < 3; ++ks)
    afr[ks] = *reinterpret_cast<const bf16x8*>(&R1[arow * 104 + ks * 32 + lg * 8]);

  const float qscale = 0.17677669529663687f;  // 32^-0.5
  // Q -> R1 (tramples Xb; afr already hoisted; band-private)
#pragma unroll
  for (int nt = 0; nt < 6; ++nt) {
    int col = nt * 16 + l16;
    f32x4 acc = zz;
#pragma unroll
    for (int ks = 0; ks < 3; ++ks)
      acc = MFMA(afr[ks], *reinterpret_cast<const bf16x8*>(&qkvw[col * 96 + ks * 32 + lg * 8]), acc);
    float bc = qkvb[col];
#pragma unroll
    for (int j = 0; j < 4; ++j)
      R1[(wv * 16 + lg * 4 + j) * 104 + col] = f2bf((acc[j] + bc) * qscale);
  }
  // K -> Ks
#pragma unroll
  for (int nt = 0; nt < 6; ++nt) {
    int col = 96 + nt * 16 + l16;
    f32x4 acc = zz;
#pragma unroll
    for (int ks = 0; ks < 3; ++ks)
      acc = MFMA(afr[ks], *reinterpret_cast<const bf16x8*>(&qkvw[col * 96 + ks * 32 + lg * 8]), acc);
    float bc = qkvb[col];
#pragma unroll
    for (int j = 0; j < 4; ++j)
      Ks[(wv * 16 + lg * 4 + j) * 104 + nt * 16 + l16] = f2bf(acc[j] + bc);
  }
  // V -> Vt (transposed)
#pragma unroll
  for (int nt = 0; nt < 6; ++nt) {
    int col = 192 + nt * 16 + l16;
    f32x4 acc = zz;
#pragma unroll
    for (int ks = 0; ks < 3; ++ks)
      acc = MFMA(afr[ks], *reinterpret_cast<const bf16x8*>(&qkvw[col * 96 + ks * 32 + lg * 8]), acc);
    float bc = qkvb[col];
#pragma unroll
    for (int j = 0; j < 4; ++j)
      Vt[(nt * 16 + l16) * 72 + wv * 16 + lg * 4 + j] = f2bf(acc[j] + bc);
  }
  __syncthreads();   // the ONE barrier: Ks/Vt are read cross-wave

  // ---- Laplacian bias in registers ----
  float bias_r[4][4];
  {
    const float a = lapA[0], bb = lapB[0];
    const float A2 = a * a;
    const float nh = -0.5f / (bb * bb);
#pragma unroll
    for (int j = 0; j < 4; ++j) {
      int qi = wv * 16 + lg * 4 + j;
      int qr = qi >> 3, qc = qi & 7;
#pragma unroll
      for (int kt = 0; kt < 4; ++kt) {
        int key = kt * 16 + l16;
        int dd = abs(qr - (key >> 3)) + abs(qc - (key & 7));
        bias_r[j][kt] = A2 * __expf(nh * (float)dd);
      }
    }
  }

  // hoist all Q A-frags (Q in R1 dies; P can then reuse the space)
  bf16x8 aqh[3];
#pragma unroll
  for (int h = 0; h < 3; ++h)
    aqh[h] = *reinterpret_cast<const bf16x8*>(&R1[arow * 104 + h * 32 + lg * 8]);

  f32x4 oacc[6];
#pragma unroll
  for (int i = 0; i < 6; ++i) oacc[i] = zz;

#pragma unroll 1
  for (int h = 0; h < 3; ++h) {
    f32x4 sc[4];
#pragma unroll
    for (int kt = 0; kt < 4; ++kt) {
      bf16x8 bk = *reinterpret_cast<const bf16x8*>(&Ks[(kt * 16 + l16) * 104 + h * 32 + lg * 8]);
      sc[kt] = MFMA(aqh[h], bk, zz);
    }
    // softmax over 64 keys (no max-subtract: |scores| bounded by ~O(5), fp32 exp safe)
#pragma unroll
    for (int j = 0; j < 4; ++j) {
      int qi = wv * 16 + lg * 4 + j;
      float e0 = __expf(sc[0][j] + bias_r[j][0]);
      float e1 = __expf(sc[1][j] + bias_r[j][1]);
      float e2 = __expf(sc[2][j] + bias_r[j][2]);
      float e3 = __expf(sc[3][j] + bias_r[j][3]);
      float s = e0 + e1 + e2 + e3;
#pragma unroll
      for (int off = 1; off < 16; off <<= 1) s += __shfl_xor(s, off);
      float inv = 1.0f / s;
      R1[qi * 104 +  0 + l16] = f2bf(e0 * inv);
      R1[qi * 104 + 16 + l16] = f2bf(e1 * inv);
      R1[qi * 104 + 32 + l16] = f2bf(e2 * inv);
      R1[qi * 104 + 48 + l16] = f2bf(e3 * inv);
    }
    // PV (P band is wave-private)
    bf16x8 ap0 = *reinterpret_cast<const bf16x8*>(&R1[arow * 104 +  0 + lg * 8]);
    bf16x8 ap1 = *reinterpret_cast<const bf16x8*>(&R1[arow * 104 + 32 + lg * 8]);
#pragma unroll
    for (int dt = 0; dt < 2; ++dt) {
      int vcol = h * 32 + dt * 16 + l16;
      bf16x8 bv0 = *reinterpret_cast<const bf16x8*>(&Vt[vcol * 72 +  0 + lg * 8]);
      bf16x8 bv1 = *reinterpret_cast<const bf16x8*>(&Vt[vcol * 72 + 32 + lg * 8]);
      oacc[h * 2 + dt] = MFMA(ap0, bv0, oacc[h * 2 + dt]);
      oacc[h * 2 + dt] = MFMA(ap1, bv1, oacc[h * 2 + dt]);
    }
  }
  // O -> R1 (tramples P; band-private)
#pragma unroll
  for (int i = 0; i < 6; ++i)
#pragma unroll
    for (int j = 0; j < 4; ++j)
      R1[(wv * 16 + lg * 4 + j) * 104 + i * 16 + l16] = f2bf(oacc[i][j]);

  // ---- proj -> R1 band (C-layout, band-private) ----
  bf16x8 ao[3];
#pragma unroll
  for (int ks = 0; ks < 3; ++ks)
    ao[ks] = *reinterpret_cast<const bf16x8*>(&R1[arow * 104 + ks * 32 + lg * 8]);
#pragma unroll
  for (int nt = 0; nt < 6; ++nt) {
    int col = nt * 16 + l16;
    f32x4 acc = zz;
#pragma unroll
    for (int ks = 0; ks < 3; ++ks)
      acc = MFMA(ao[ks], *reinterpret_cast<const bf16x8*>(&projw[col * 96 + ks * 32 + lg * 8]), acc);
    float pb = projb[col];
#pragma unroll
    for (int j = 0; j < 4; ++j)
      R1[(wv * 16 + lg * 4 + j) * 104 + col] = f2bf(acc[j] + pb);
  }
  // ---- read back own token, add raw fp32 shortcut, contiguous bf16 store ----
  {
    const int rh = hi * 8 + (t >> 3);
    const int rw = ((wi * 8 + (t & 7)) + sh) & 511;   // original pixel coords
    unsigned short* xo = &xt[(size_t)(((b << 18) + (rh << 9) + rw)) * 96 + q * 24];
#pragma unroll
    for (int v = 0; v < 3; ++v) {
      bf16x8 m = *reinterpret_cast<const bf16x8*>(&R1[t * 104 + q * 24 + v * 8]);
      bf16x8 pk;
#pragma unroll
      for (int e = 0; e < 8; ++e)
        pk[e] = (short)f2bf(bf2f((unsigned short)m[e]) + xreg[v * 8 + e]);
      *reinterpret_cast<bf16x8*>(&xo[v * 8]) = pk;
    }
  }
}

// ---------------------------------------------------------------------------
// Kernel 2: per 64-token strip  LN2 + MLP + residual + planar store
// Input xt is token-major -> fully contiguous loads, no shift logic.
// grid = 8192, block = 256.  LDS 13312 B, VGPR ~40, 0 barriers -> 8 blocks/CU.
// ---------------------------------------------------------------------------
__global__ __launch_bounds__(256, 8) void k_mlp(
    const unsigned short* __restrict__ xt,     // bf16 [2*512*512][96]
    const float* __restrict__ ln2g, const float* __restrict__ ln2b,
    const unsigned short* __restrict__ w1,     // bf16 [384][96]
    const float* __restrict__ b1,
    const unsigned short* __restrict__ w2,     // bf16 [96][384]
    const float* __restrict__ b2,
    float* __restrict__ out)
{
  // S multiplexes (stride 104, rows wave-band-private): Xb -> Hl(96-chunk) -> mlp_out(bf16)
  __shared__ __align__(16) unsigned short S[64 * 104];

  const int tid = threadIdx.x;
  const int bid = blockIdx.x;
  const int b  = bid >> 12;
  const int h  = (bid >> 3) & 511;
  const int w0 = (bid & 7) << 6;
  const int q    = tid & 3;
  const int t    = tid >> 2;      // owned token 0..63 (in own wave's band)
  const int lane = tid & 63;
  const int wv   = tid >> 6;
  const int l16  = lane & 15;
  const int lg   = lane >> 4;
  const int arow = wv * 16 + l16;
  const f32x4 zz = {0.f, 0.f, 0.f, 0.f};

  const unsigned short* xp = &xt[((b << 18) + (h << 9) + w0 + t) * 96 + q * 24];

  // ---- contiguous xt load ----
  float xv[24];
#pragma unroll
  for (int v = 0; v < 3; ++v) {
    bf16x8 g = *reinterpret_cast<const bf16x8*>(&xp[v * 8]);
#pragma unroll
    for (int e = 0; e < 8; ++e) xv[v * 8 + e] = bf2f((unsigned short)g[e]);
  }
  // ---- LN2 via quad shuffles ----
  float mu, rs;
  {
    float s1 = 0.f, s2 = 0.f;
#pragma unroll
    for (int k = 0; k < 24; ++k) { float v = xv[k]; s1 += v; s2 += v * v; }
    s1 += __shfl_xor(s1, 1); s2 += __shfl_xor(s2, 1);
    s1 += __shfl_xor(s1, 2); s2 += __shfl_xor(s2, 2);
    mu = s1 * (1.f / 96.f);
    rs = rsqrtf(s2 * (1.f / 96.f) - mu * mu + 1e-5f);
  }
#pragma unroll
  for (int v = 0; v < 3; ++v) {
    bf16x8 pk;
#pragma unroll
    for (int e = 0; e < 8; ++e) {
      int c = q * 24 + v * 8 + e;
      pk[e] = (short)f2bf((xv[v * 8 + e] - mu) * rs * ln2g[c] + ln2b[c]);
    }
    *reinterpret_cast<bf16x8*>(&S[t * 104 + q * 24 + v * 8]) = pk;
  }
  // xv dies here -> low register pressure in the GEMM loops

  // ---- A-frags of LN2(xt); then S rows are free for Hl ----
  bf16x8 a1[3];
#pragma unroll
  for (int ks = 0; ks < 3; ++ks)
    a1[ks] = *reinterpret_cast<const bf16x8*>(&S[arow * 104 + ks * 32 + lg * 8]);

  f32x4 acc2[6];
#pragma unroll
  for (int i = 0; i < 6; ++i) acc2[i] = zz;

  // ---- hidden dim in 4 chunks of 96: GEMM1+GELU -> S band -> GEMM2 accum ----
#pragma unroll 1
  for (int ch = 0; ch < 4; ++ch) {
#pragma unroll 2
    for (int nt = 0; nt < 6; ++nt) {
      int col = ch * 96 + nt * 16 + l16;
      f32x4 acc = zz;
#pragma unroll
      for (int ks = 0; ks < 3; ++ks)
        acc = MFMA(a1[ks], *reinterpret_cast<const bf16x8*>(&w1[col * 96 + ks * 32 + lg * 8]), acc);
      float bb = b1[col];
#pragma unroll
      for (int j = 0; j < 4; ++j) {
        int row = wv * 16 + lg * 4 + j;
        float v = acc[j] + bb;
        // gelu(v) ~= v * sigmoid(1.5957691 v + 0.071354816 v^3)
        float tt = v * fmaf(0.071354816f, v * v, 1.5957691f);
        float g = v * __builtin_amdgcn_rcpf(1.f + __expf(-tt));
        S[row * 104 + nt * 16 + l16] = f2bf(g);
      }
    }
    bf16x8 ah[3];
#pragma unroll
    for (int ks = 0; ks < 3; ++ks)
      ah[ks] = *reinterpret_cast<const bf16x8*>(&S[arow * 104 + ks * 32 + lg * 8]);
#pragma unroll
    for (int nt = 0; nt < 6; ++nt) {
      int col = nt * 16 + l16;
#pragma unroll
      for (int ks = 0; ks < 3; ++ks)
        acc2[nt] = MFMA(ah[ks], *reinterpret_cast<const bf16x8*>(&w2[col * 384 + ch * 96 + ks * 32 + lg * 8]), acc2[nt]);
    }
  }

  // ---- epilogue: mlp_out (bf16) -> S band; read back in ownership layout ----
#pragma unroll
  for (int nt = 0; nt < 6; ++nt) {
    int col = nt * 16 + l16;
    float bb = b2[col];
#pragma unroll
    for (int j = 0; j < 4; ++j)
      S[(wv * 16 + lg * 4 + j) * 104 + col] = f2bf(acc2[nt][j] + bb);
  }
#pragma unroll
  for (int v = 0; v < 3; ++v) {
    bf16x8 m = *reinterpret_cast<const bf16x8*>(&S[t * 104 + q * 24 + v * 8]);
    bf16x8 g = *reinterpret_cast<const bf16x8*>(&xp[v * 8]);   // L1/L2-hot re-read
#pragma unroll
    for (int e = 0; e < 8; ++e) {
      int c = q * 24 + v * 8 + e;
      out[((b * 96 + c) << 18) + (h << 9) + w0 + t] =
          bf2f((unsigned short)g[e]) + bf2f((unsigned short)m[e]);
    }
  }
}

// ---------------------------------------------------------------------------
extern "C" void kernel_launch(void* const* d_in, const int* in_sizes, int n_in,
                              void* d_out, int out_size, void* d_ws, size_t ws_size,
                              hipStream_t stream) {
  const float* x     = (const float*)d_in[0];
  const float* ln1g  = (const float*)d_in[1];
  const float* ln1b  = (const float*)d_in[2];
  const float* qkv_w = (const float*)d_in[3];
  const float* qkv_b = (const float*)d_in[4];
  const float* lapA  = (const float*)d_in[5];
  const float* lapB  = (const float*)d_in[6];
  const float* prj_w = (const float*)d_in[7];
  const float* prj_b = (const float*)d_in[8];
  const float* ln2g  = (const float*)d_in[9];
  const float* ln2b  = (const float*)d_in[10];
  const float* w1f   = (const float*)d_in[11];
  const float* b1    = (const float*)d_in[12];
  const float* w2f   = (const float*)d_in[13];
  const float* b2    = (const float*)d_in[14];

  char* ws = (char*)d_ws;
  unsigned short* xtb   = (unsigned short*)ws;                 // bf16 [524288][96]
  unsigned short* qkvwb = (unsigned short*)(ws + 100663296);
  unsigned short* prjwb = (unsigned short*)(ws + 100718592);
  unsigned short* w1b   = (unsigned short*)(ws + 100737024);
  unsigned short* w2b   = (unsigned short*)(ws + 100810752);

  k_cvt<<<64, 256, 0, stream>>>(qkv_w, qkvwb, 288 * 96);
  k_cvt<<<64, 256, 0, stream>>>(prj_w, prjwb, 96 * 96);
  k_cvt<<<64, 256, 0, stream>>>(w1f,   w1b,   384 * 96);
  k_cvt<<<64, 256, 0, stream>>>(w2f,   w2b,   96 * 384);

  k_attn<<<8192, 256, 0, stream>>>(x, ln1g, ln1b, qkvwb, qkv_b, lapA, lapB,
                                   prjwb, prj_b, xtb);
  k_mlp<<<8192, 256, 0, stream>>>(xtb, ln2g, ln2b, w1b, b1, w2b, b2,
                                  (float*)d_out);
}

// Round 6
// 642.177 us; speedup vs baseline: 1.3448x; 1.3448x over previous
//
#include <hip/hip_runtime.h>

#define SHIFT 4

typedef short bf16x8 __attribute__((ext_vector_type(8)));
typedef float f32x4  __attribute__((ext_vector_type(4)));

#define MFMA(a, b, c) __builtin_amdgcn_mfma_f32_16x16x32_bf16((a), (b), (c), 0, 0, 0)

__device__ __forceinline__ unsigned short f2bf(float f) {
  unsigned int u = __float_as_uint(f);
  u += 0x7fffu + ((u >> 16) & 1u);   // round-to-nearest-even; inputs finite
  return (unsigned short)(u >> 16);
}
__device__ __forceinline__ float bf2f(unsigned short u) {
  return __uint_as_float(((unsigned int)u) << 16);
}

// ---------------------------------------------------------------------------
// Kernel 0a: fp32 -> bf16 weight conversion (linear)
// ---------------------------------------------------------------------------
__global__ void k_cvt(const float* __restrict__ s, unsigned short* __restrict__ d, int n) {
  int i = blockIdx.x * blockDim.x + threadIdx.x;
  int st = gridDim.x * blockDim.x;
  for (; i < n; i += st) d[i] = f2bf(s[i]);
}

// ---------------------------------------------------------------------------
// Kernel 0b: fp32 -> bf16 + permute w1 [384][96] -> [cb][ks][16][32] tiles
//   dst[((col>>4)*3 + (k>>5))*512 + (col&15)*32 + (k&31)]
// ---------------------------------------------------------------------------
__global__ void k_cvt_p1(const float* __restrict__ s, unsigned short* __restrict__ d) {
  int i = blockIdx.x * 256 + threadIdx.x;
  if (i < 36864) {
    int col = i / 96, k = i - col * 96;
    d[(((col >> 4) * 3 + (k >> 5)) << 9) + ((col & 15) << 5) + (k & 31)] = f2bf(s[i]);
  }
}
// w2 [96][384] -> [cb][12 ks][16][32]
__global__ void k_cvt_p2(const float* __restrict__ s, unsigned short* __restrict__ d) {
  int i = blockIdx.x * 256 + threadIdx.x;
  if (i < 36864) {
    int col = i / 384, k = i - col * 384;
    d[(((col >> 4) * 12 + (k >> 5)) << 9) + ((col & 15) << 5) + (k & 31)] = f2bf(s[i]);
  }
}

// ---------------------------------------------------------------------------
// Kernel 1: per-window  LN1 + shift-gather + QKV + attention + proj + shortcut
// Emits xt = x + attn (bf16, TOKEN-MAJOR [B*HW][96], original coordinates).
// grid = 8192, block = 256 (4 waves; wave = 16-row M-tile). 1 barrier.
// LDS = R1(13312)+Ks(13312)+Vt(13824) = 40448 B -> 4 blocks/CU
// ---------------------------------------------------------------------------
__global__ __launch_bounds__(256, 4) void k_attn(
    const float* __restrict__ x,
    const float* __restrict__ ln1g, const float* __restrict__ ln1b,
    const unsigned short* __restrict__ qkvw,   // bf16 [288][96]
    const float* __restrict__ qkvb,
    const float* __restrict__ lapA, const float* __restrict__ lapB,
    const unsigned short* __restrict__ projw,  // bf16 [96][96]
    const float* __restrict__ projb,
    unsigned short* __restrict__ xt)           // bf16 [2*512*512][96]
{
  // R1 multiplexes (stride 104, rows wave-band-private): Xb -> Q -> P -> O -> proj
  __shared__ __align__(16) unsigned short R1[64 * 104];
  __shared__ __align__(16) unsigned short Ks[64 * 104];
  __shared__ __align__(16) unsigned short Vt[96 * 72];   // V^T [d][key(+pad)]

  const int tid = threadIdx.x;
  const int wid = blockIdx.x;
  const int b   = wid >> 12;
  const int hi  = (wid >> 6) & 63;
  const int wi  = wid & 63;
  const int q   = tid & 3;        // channel quarter (24 channels)
  const int t   = tid >> 2;       // owned token 0..63 (inside own wave's band)
  const int lane = tid & 63;
  const int wv   = tid >> 6;
  const int l16  = lane & 15;
  const int lg   = lane >> 4;
  const int arow = wv * 16 + l16;
  const f32x4 zz = {0.f, 0.f, 0.f, 0.f};

  const int sh = ((hi & 1) == 0) ? -SHIFT : SHIFT;   // gather source offset

  // ---- shifted gather into registers: thread owns (t, c = q*24 + k) ----
  // xreg stays live to the end (it IS the shortcut at this token's position).
  float xreg[24];
  {
    const int hh = hi * 8 + (t >> 3);
    const int ww = ((wi * 8 + (t & 7)) + sh) & 511;
    const float* xp = x + (hh << 9) + ww;
#pragma unroll
    for (int k = 0; k < 24; ++k)
      xreg[k] = xp[(b * 96 + q * 24 + k) << 18];
  }
  // ---- LN1 stats via quad shuffles ----
  float mu, rs;
  {
    float s1 = 0.f, s2 = 0.f;
#pragma unroll
    for (int k = 0; k < 24; ++k) { float v = xreg[k]; s1 += v; s2 += v * v; }
    s1 += __shfl_xor(s1, 1); s2 += __shfl_xor(s2, 1);
    s1 += __shfl_xor(s1, 2); s2 += __shfl_xor(s2, 2);
    mu = s1 * (1.f / 96.f);
    rs = rsqrtf(s2 * (1.f / 96.f) - mu * mu + 1e-5f);
  }
  // ---- Xb into R1 (vectorized, band-private) ----
#pragma unroll
  for (int v = 0; v < 3; ++v) {
    bf16x8 pk;
#pragma unroll
    for (int e = 0; e < 8; ++e) {
      int c = q * 24 + v * 8 + e;
      pk[e] = (short)f2bf((xreg[v * 8 + e] - mu) * rs * ln1g[c] + ln1b[c]);
    }
    *reinterpret_cast<bf16x8*>(&R1[t * 104 + q * 24 + v * 8]) = pk;
  }

  // ---- QKV GEMM: [64,96] @ [96,288]^T  (A-frags from own band; no barrier) ----
  bf16x8 afr[3];
#pragma unroll
  for (int ks = 0; ks < 3; ++ks)
    afr[ks] = *reinterpret_cast<const bf16x8*>(&R1[arow * 104 + ks * 32 + lg * 8]);

  const float qscale = 0.17677669529663687f;  // 32^-0.5
  // Q -> R1 (tramples Xb; afr already hoisted; band-private)
#pragma unroll
  for (int nt = 0; nt < 6; ++nt) {
    int col = nt * 16 + l16;
    f32x4 acc = zz;
#pragma unroll
    for (int ks = 0; ks < 3; ++ks)
      acc = MFMA(afr[ks], *reinterpret_cast<const bf16x8*>(&qkvw[col * 96 + ks * 32 + lg * 8]), acc);
    float bc = qkvb[col];
#pragma unroll
    for (int j = 0; j < 4; ++j)
      R1[(wv * 16 + lg * 4 + j) * 104 + col] = f2bf((acc[j] + bc) * qscale);
  }
  // K -> Ks
#pragma unroll
  for (int nt = 0; nt < 6; ++nt) {
    int col = 96 + nt * 16 + l16;
    f32x4 acc = zz;
#pragma unroll
    for (int ks = 0; ks < 3; ++ks)
      acc = MFMA(afr[ks], *reinterpret_cast<const bf16x8*>(&qkvw[col * 96 + ks * 32 + lg * 8]), acc);
    float bc = qkvb[col];
#pragma unroll
    for (int j = 0; j < 4; ++j)
      Ks[(wv * 16 + lg * 4 + j) * 104 + nt * 16 + l16] = f2bf(acc[j] + bc);
  }
  // V -> Vt (transposed)
#pragma unroll
  for (int nt = 0; nt < 6; ++nt) {
    int col = 192 + nt * 16 + l16;
    f32x4 acc = zz;
#pragma unroll
    for (int ks = 0; ks < 3; ++ks)
      acc = MFMA(afr[ks], *reinterpret_cast<const bf16x8*>(&qkvw[col * 96 + ks * 32 + lg * 8]), acc);
    float bc = qkvb[col];
#pragma unroll
    for (int j = 0; j < 4; ++j)
      Vt[(nt * 16 + l16) * 72 + wv * 16 + lg * 4 + j] = f2bf(acc[j] + bc);
  }
  __syncthreads();   // the ONE barrier: Ks/Vt are read cross-wave

  // ---- Laplacian bias in registers ----
  float bias_r[4][4];
  {
    const float a = lapA[0], bb = lapB[0];
    const float A2 = a * a;
    const float nh = -0.5f / (bb * bb);
#pragma unroll
    for (int j = 0; j < 4; ++j) {
      int qi = wv * 16 + lg * 4 + j;
      int qr = qi >> 3, qc = qi & 7;
#pragma unroll
      for (int kt = 0; kt < 4; ++kt) {
        int key = kt * 16 + l16;
        int dd = abs(qr - (key >> 3)) + abs(qc - (key & 7));
        bias_r[j][kt] = A2 * __expf(nh * (float)dd);
      }
    }
  }

  // hoist all Q A-frags (Q in R1 dies; P can then reuse the space)
  bf16x8 aqh[3];
#pragma unroll
  for (int h = 0; h < 3; ++h)
    aqh[h] = *reinterpret_cast<const bf16x8*>(&R1[arow * 104 + h * 32 + lg * 8]);

  f32x4 oacc[6];
#pragma unroll
  for (int i = 0; i < 6; ++i) oacc[i] = zz;

#pragma unroll 1
  for (int h = 0; h < 3; ++h) {
    f32x4 sc[4];
#pragma unroll
    for (int kt = 0; kt < 4; ++kt) {
      bf16x8 bk = *reinterpret_cast<const bf16x8*>(&Ks[(kt * 16 + l16) * 104 + h * 32 + lg * 8]);
      sc[kt] = MFMA(aqh[h], bk, zz);
    }
    // softmax over 64 keys (no max-subtract: scores bounded, fp32 exp safe)
#pragma unroll
    for (int j = 0; j < 4; ++j) {
      int qi = wv * 16 + lg * 4 + j;
      float e0 = __expf(sc[0][j] + bias_r[j][0]);
      float e1 = __expf(sc[1][j] + bias_r[j][1]);
      float e2 = __expf(sc[2][j] + bias_r[j][2]);
      float e3 = __expf(sc[3][j] + bias_r[j][3]);
      float s = e0 + e1 + e2 + e3;
#pragma unroll
      for (int off = 1; off < 16; off <<= 1) s += __shfl_xor(s, off);
      float inv = 1.0f / s;
      R1[qi * 104 +  0 + l16] = f2bf(e0 * inv);
      R1[qi * 104 + 16 + l16] = f2bf(e1 * inv);
      R1[qi * 104 + 32 + l16] = f2bf(e2 * inv);
      R1[qi * 104 + 48 + l16] = f2bf(e3 * inv);
    }
    // PV (P band is wave-private)
    bf16x8 ap0 = *reinterpret_cast<const bf16x8*>(&R1[arow * 104 +  0 + lg * 8]);
    bf16x8 ap1 = *reinterpret_cast<const bf16x8*>(&R1[arow * 104 + 32 + lg * 8]);
#pragma unroll
    for (int dt = 0; dt < 2; ++dt) {
      int vcol = h * 32 + dt * 16 + l16;
      bf16x8 bv0 = *reinterpret_cast<const bf16x8*>(&Vt[vcol * 72 +  0 + lg * 8]);
      bf16x8 bv1 = *reinterpret_cast<const bf16x8*>(&Vt[vcol * 72 + 32 + lg * 8]);
      oacc[h * 2 + dt] = MFMA(ap0, bv0, oacc[h * 2 + dt]);
      oacc[h * 2 + dt] = MFMA(ap1, bv1, oacc[h * 2 + dt]);
    }
  }
  // O -> R1 (tramples P; band-private)
#pragma unroll
  for (int i = 0; i < 6; ++i)
#pragma unroll
    for (int j = 0; j < 4; ++j)
      R1[(wv * 16 + lg * 4 + j) * 104 + i * 16 + l16] = f2bf(oacc[i][j]);

  // ---- proj -> R1 band (C-layout, band-private) ----
  bf16x8 ao[3];
#pragma unroll
  for (int ks = 0; ks < 3; ++ks)
    ao[ks] = *reinterpret_cast<const bf16x8*>(&R1[arow * 104 + ks * 32 + lg * 8]);
#pragma unroll
  for (int nt = 0; nt < 6; ++nt) {
    int col = nt * 16 + l16;
    f32x4 acc = zz;
#pragma unroll
    for (int ks = 0; ks < 3; ++ks)
      acc = MFMA(ao[ks], *reinterpret_cast<const bf16x8*>(&projw[col * 96 + ks * 32 + lg * 8]), acc);
    float pb = projb[col];
#pragma unroll
    for (int j = 0; j < 4; ++j)
      R1[(wv * 16 + lg * 4 + j) * 104 + col] = f2bf(acc[j] + pb);
  }
  // ---- read back own token, add raw fp32 shortcut, contiguous bf16 store ----
  {
    const int rh = hi * 8 + (t >> 3);
    const int rw = ((wi * 8 + (t & 7)) + sh) & 511;   // original pixel coords
    unsigned short* xo = &xt[(size_t)(((b << 18) + (rh << 9) + rw)) * 96 + q * 24];
#pragma unroll
    for (int v = 0; v < 3; ++v) {
      bf16x8 m = *reinterpret_cast<const bf16x8*>(&R1[t * 104 + q * 24 + v * 8]);
      bf16x8 pk;
#pragma unroll
      for (int e = 0; e < 8; ++e)
        pk[e] = (short)f2bf(bf2f((unsigned short)m[e]) + xreg[v * 8 + e]);
      *reinterpret_cast<bf16x8*>(&xo[v * 8]) = pk;
    }
  }
}

// ---------------------------------------------------------------------------
// Kernel 2: weight-stationary MLP.  Block stages ALL of w1+w2 in LDS (147456 B)
// + S (13312 B) = 160768 B -> 1 block/CU.  grid = 1024, each block does 8
// 64-token strips with ZERO barriers in the loop (S rows wave-band-private).
// B-frags come from LDS in permuted conflict-free tiles.
// ---------------------------------------------------------------------------
__global__ __launch_bounds__(256, 1) void k_mlp(
    const unsigned short* __restrict__ xt,     // bf16 [2*512*512][96]
    const float* __restrict__ ln2g, const float* __restrict__ ln2b,
    const unsigned short* __restrict__ w1p,    // bf16 permuted [24cb][3ks][16][32]
    const float* __restrict__ b1,
    const unsigned short* __restrict__ w2p,    // bf16 permuted [6cb][12ks][16][32]
    const float* __restrict__ b2,
    float* __restrict__ out)
{
  __shared__ __align__(16) unsigned short Wl[36864];   // w1 tiles
  __shared__ __align__(16) unsigned short W2l[36864];  // w2 tiles
  __shared__ __align__(16) unsigned short S[6656];     // [64][104] multiplex

  const int tid = threadIdx.x;
  const int bid = blockIdx.x;
  const int q    = tid & 3;
  const int t    = tid >> 2;      // owned token 0..63 (in own wave's band)
  const int lane = tid & 63;
  const int wv   = tid >> 6;
  const int l16  = lane & 15;
  const int lg   = lane >> 4;
  const int arow = wv * 16 + l16;
  const f32x4 zz = {0.f, 0.f, 0.f, 0.f};

  // ---- stage all weights into LDS (once per block) ----
#pragma unroll
  for (int it = 0; it < 18; ++it) {
    int o = (it * 256 + tid) * 8;
    *reinterpret_cast<bf16x8*>(&Wl[o])  = *reinterpret_cast<const bf16x8*>(&w1p[o]);
    *reinterpret_cast<bf16x8*>(&W2l[o]) = *reinterpret_cast<const bf16x8*>(&w2p[o]);
  }

  // ---- loop-invariant preloads ----
  float gr[24], br[24], b1r[24], b2r[6];
#pragma unroll
  for (int k = 0; k < 24; ++k) { gr[k] = ln2g[q * 24 + k]; br[k] = ln2b[q * 24 + k]; }
#pragma unroll
  for (int cc = 0; cc < 24; ++cc) b1r[cc] = b1[cc * 16 + l16];
#pragma unroll
  for (int n = 0; n < 6; ++n) b2r[n] = b2[n * 16 + l16];

  __syncthreads();   // weights staged (the only barrier)

#pragma unroll 1
  for (int s = 0; s < 8; ++s) {
    const int sid = (bid << 3) + s;
    const int b  = sid >> 12;
    const int h  = (sid >> 3) & 511;
    const int w0 = (sid & 7) << 6;
    const unsigned short* xp = &xt[(size_t)((b << 18) + (h << 9) + w0 + t) * 96 + q * 24];

    // ---- contiguous xt load (also the residual) ----
    float xv[24];
#pragma unroll
    for (int v = 0; v < 3; ++v) {
      bf16x8 g = *reinterpret_cast<const bf16x8*>(&xp[v * 8]);
#pragma unroll
      for (int e = 0; e < 8; ++e) xv[v * 8 + e] = bf2f((unsigned short)g[e]);
    }
    // ---- LN2 via quad shuffles ----
    float mu, rs;
    {
      float s1 = 0.f, s2 = 0.f;
#pragma unroll
      for (int k = 0; k < 24; ++k) { float v = xv[k]; s1 += v; s2 += v * v; }
      s1 += __shfl_xor(s1, 1); s2 += __shfl_xor(s2, 1);
      s1 += __shfl_xor(s1, 2); s2 += __shfl_xor(s2, 2);
      mu = s1 * (1.f / 96.f);
      rs = rsqrtf(s2 * (1.f / 96.f) - mu * mu + 1e-5f);
    }
#pragma unroll
    for (int v = 0; v < 3; ++v) {
      bf16x8 pk;
#pragma unroll
      for (int e = 0; e < 8; ++e)
        pk[e] = (short)f2bf((xv[v * 8 + e] - mu) * rs * gr[v * 8 + e] + br[v * 8 + e]);
      *reinterpret_cast<bf16x8*>(&S[t * 104 + q * 24 + v * 8]) = pk;
    }

    // ---- A-frags of LN2(xt); then S rows are free for Hl ----
    bf16x8 a1[3];
#pragma unroll
    for (int ks = 0; ks < 3; ++ks)
      a1[ks] = *reinterpret_cast<const bf16x8*>(&S[arow * 104 + ks * 32 + lg * 8]);

    f32x4 acc2[6];
#pragma unroll
    for (int i = 0; i < 6; ++i) acc2[i] = zz;

    // ---- hidden dim in 4 chunks of 96 (fully unrolled: static indexing) ----
#pragma unroll
    for (int ch = 0; ch < 4; ++ch) {
#pragma unroll
      for (int nt = 0; nt < 6; ++nt) {
        f32x4 acc = zz;
#pragma unroll
        for (int ks = 0; ks < 3; ++ks)
          acc = MFMA(a1[ks],
                     *reinterpret_cast<const bf16x8*>(&Wl[(((ch * 6 + nt) * 3 + ks) << 9) + (l16 << 5) + lg * 8]),
                     acc);
        float bb = b1r[ch * 6 + nt];
#pragma unroll
        for (int j = 0; j < 4; ++j) {
          int row = wv * 16 + lg * 4 + j;
          float v = acc[j] + bb;
          // gelu(v) ~= v * sigmoid(1.5957691 v + 0.071354816 v^3)
          float tt = v * fmaf(0.071354816f, v * v, 1.5957691f);
          float g = v * __builtin_amdgcn_rcpf(1.f + __expf(-tt));
          S[row * 104 + nt * 16 + l16] = f2bf(g);
        }
      }
      bf16x8 ah[3];
#pragma unroll
      for (int ks = 0; ks < 3; ++ks)
        ah[ks] = *reinterpret_cast<const bf16x8*>(&S[arow * 104 + ks * 32 + lg * 8]);
#pragma unroll
      for (int nt = 0; nt < 6; ++nt) {
#pragma unroll
        for (int ks = 0; ks < 3; ++ks)
          acc2[nt] = MFMA(ah[ks],
                          *reinterpret_cast<const bf16x8*>(&W2l[(((nt * 12 + ch * 3 + ks)) << 9) + (l16 << 5) + lg * 8]),
                          acc2[nt]);
      }
    }

    // ---- epilogue: mlp_out (bf16) -> S band; read back in ownership layout ----
#pragma unroll
    for (int nt = 0; nt < 6; ++nt) {
      float bb = b2r[nt];
#pragma unroll
      for (int j = 0; j < 4; ++j)
        S[(wv * 16 + lg * 4 + j) * 104 + nt * 16 + l16] = f2bf(acc2[nt][j] + bb);
    }
#pragma unroll
    for (int v = 0; v < 3; ++v) {
      bf16x8 m = *reinterpret_cast<const bf16x8*>(&S[t * 104 + q * 24 + v * 8]);
#pragma unroll
      for (int e = 0; e < 8; ++e) {
        int c = q * 24 + v * 8 + e;
        out[((b * 96 + c) << 18) + (h << 9) + w0 + t] =
            xv[v * 8 + e] + bf2f((unsigned short)m[e]);
      }
    }
  }
}

// ---------------------------------------------------------------------------
extern "C" void kernel_launch(void* const* d_in, const int* in_sizes, int n_in,
                              void* d_out, int out_size, void* d_ws, size_t ws_size,
                              hipStream_t stream) {
  const float* x     = (const float*)d_in[0];
  const float* ln1g  = (const float*)d_in[1];
  const float* ln1b  = (const float*)d_in[2];
  const float* qkv_w = (const float*)d_in[3];
  const float* qkv_b = (const float*)d_in[4];
  const float* lapA  = (const float*)d_in[5];
  const float* lapB  = (const float*)d_in[6];
  const float* prj_w = (const float*)d_in[7];
  const float* prj_b = (const float*)d_in[8];
  const float* ln2g  = (const float*)d_in[9];
  const float* ln2b  = (const float*)d_in[10];
  const float* w1f   = (const float*)d_in[11];
  const float* b1    = (const float*)d_in[12];
  const float* w2f   = (const float*)d_in[13];
  const float* b2    = (const float*)d_in[14];

  char* ws = (char*)d_ws;
  unsigned short* xtb   = (unsigned short*)ws;                 // bf16 [524288][96]
  unsigned short* qkvwb = (unsigned short*)(ws + 100663296);
  unsigned short* prjwb = (unsigned short*)(ws + 100718592);
  unsigned short* w1p   = (unsigned short*)(ws + 100737024);   // permuted tiles
  unsigned short* w2p   = (unsigned short*)(ws + 100810752);   // permuted tiles

  k_cvt   <<<64, 256, 0, stream>>>(qkv_w, qkvwb, 288 * 96);
  k_cvt   <<<64, 256, 0, stream>>>(prj_w, prjwb, 96 * 96);
  k_cvt_p1<<<144, 256, 0, stream>>>(w1f, w1p);
  k_cvt_p2<<<144, 256, 0, stream>>>(w2f, w2p);

  k_attn<<<8192, 256, 0, stream>>>(x, ln1g, ln1b, qkvwb, qkv_b, lapA, lapB,
                                   prjwb, prj_b, xtb);
  k_mlp<<<1024, 256, 0, stream>>>(xtb, ln2g, ln2b, w1p, b1, w2p, b2,
                                  (float*)d_out);
}